// Round 1
// baseline (88.249 us; speedup 1.0000x reference)
//
#include <hip/hip_runtime.h>

#define BB 4
#define NN 4096
#define TI 256      // threads per block = i's per block
#define CHUNK 256   // j's staged in LDS per pass
#define MAXJB 16

#if __has_builtin(__builtin_amdgcn_sqrtf)
  #define FAST_SQRT __builtin_amdgcn_sqrtf
#else
  #define FAST_SQRT sqrtf
#endif

__device__ __forceinline__ float clip1(float x) {
    return fminf(fmaxf(x, -1.0f), 1.0f);   // -> v_med3_f32
}

// Computes per-(b,i) partial adjustment sums over the j-slice blockIdx.y.
// part layout: [jb][BB*NN*3]
__global__ __launch_bounds__(TI) void ncp_partial(
    const float* __restrict__ coords,   // [BB,NN,3]
    const float* __restrict__ radii,    // [BB,NN]
    float* __restrict__ part,
    int jb)
{
    __shared__ float4 jt[CHUNK];
    const int b = blockIdx.z;
    const int i = blockIdx.x * TI + threadIdx.x;
    const int s = blockIdx.y;
    const int jlen = NN / jb;
    const int jbase = s * jlen;

    const float xi = coords[(b * NN + i) * 3 + 0];
    const float yi = coords[(b * NN + i) * 3 + 1];
    const float zi = coords[(b * NN + i) * 3 + 2];
    const float ri = radii[b * NN + i];

    float ax = 0.0f, ay = 0.0f, az = 0.0f;

    for (int jc = 0; jc < jlen; jc += CHUNK) {
        const int jj = jbase + jc + threadIdx.x;
        __syncthreads();
        jt[threadIdx.x] = make_float4(coords[(b * NN + jj) * 3 + 0],
                                      coords[(b * NN + jj) * 3 + 1],
                                      coords[(b * NN + jj) * 3 + 2],
                                      radii[b * NN + jj]);
        __syncthreads();
        #pragma unroll 8
        for (int k = 0; k < CHUNK; ++k) {
            const float4 c = jt[k];                 // wave-uniform addr -> LDS broadcast
            const float dx = xi - c.x;
            const float dy = yi - c.y;
            const float dz = zi - c.z;
            const float d2 = fmaf(dx, dx, fmaf(dy, dy, dz * dz));
            const float dist = FAST_SQRT(d2);       // sqrt(0)=0 handles diagonal
            const float tgt = fmaxf(1.0f, ri + c.w);
            const float p = fmaxf(tgt - dist, 0.0f);
            ax = fmaf(p, clip1(dx), ax);
            ay = fmaf(p, clip1(dy), ay);
            az = fmaf(p, clip1(dz), az);
        }
    }

    float* dst = part + (size_t)s * (BB * NN * 3);
    const int o = (b * NN + i) * 3;
    dst[o + 0] = ax;
    dst[o + 1] = ay;
    dst[o + 2] = az;
}

// out[o] = coords[o] + 0.1/NN * sum_s part[s][o]
__global__ __launch_bounds__(256) void ncp_reduce(
    const float* __restrict__ coords,
    const float* __restrict__ part,
    float* __restrict__ out,
    int jb)
{
    const int o = blockIdx.x * 256 + threadIdx.x;
    if (o >= BB * NN * 3) return;
    float acc = 0.0f;
    for (int s = 0; s < jb; ++s)
        acc += part[(size_t)s * (BB * NN * 3) + o];
    out[o] = fmaf(0.1f / (float)NN, acc, coords[o]);
}

// Fallback if ws is too small: full j-loop per thread, write out directly.
__global__ __launch_bounds__(TI) void ncp_direct(
    const float* __restrict__ coords,
    const float* __restrict__ radii,
    float* __restrict__ out)
{
    __shared__ float4 jt[CHUNK];
    const int b = blockIdx.z;
    const int i = blockIdx.x * TI + threadIdx.x;

    const float xi = coords[(b * NN + i) * 3 + 0];
    const float yi = coords[(b * NN + i) * 3 + 1];
    const float zi = coords[(b * NN + i) * 3 + 2];
    const float ri = radii[b * NN + i];

    float ax = 0.0f, ay = 0.0f, az = 0.0f;

    for (int jc = 0; jc < NN; jc += CHUNK) {
        const int jj = jc + threadIdx.x;
        __syncthreads();
        jt[threadIdx.x] = make_float4(coords[(b * NN + jj) * 3 + 0],
                                      coords[(b * NN + jj) * 3 + 1],
                                      coords[(b * NN + jj) * 3 + 2],
                                      radii[b * NN + jj]);
        __syncthreads();
        #pragma unroll 8
        for (int k = 0; k < CHUNK; ++k) {
            const float4 c = jt[k];
            const float dx = xi - c.x;
            const float dy = yi - c.y;
            const float dz = zi - c.z;
            const float d2 = fmaf(dx, dx, fmaf(dy, dy, dz * dz));
            const float dist = FAST_SQRT(d2);
            const float tgt = fmaxf(1.0f, ri + c.w);
            const float p = fmaxf(tgt - dist, 0.0f);
            ax = fmaf(p, clip1(dx), ax);
            ay = fmaf(p, clip1(dy), ay);
            az = fmaf(p, clip1(dz), az);
        }
    }

    const int o = (b * NN + i) * 3;
    const float sc = 0.1f / (float)NN;
    out[o + 0] = fmaf(sc, ax, coords[o + 0]);
    out[o + 1] = fmaf(sc, ay, coords[o + 1]);
    out[o + 2] = fmaf(sc, az, coords[o + 2]);
}

extern "C" void kernel_launch(void* const* d_in, const int* in_sizes, int n_in,
                              void* d_out, int out_size, void* d_ws, size_t ws_size,
                              hipStream_t stream) {
    const float* coords = (const float*)d_in[0];
    const float* radii  = (const float*)d_in[1];
    float* out = (float*)d_out;
    const int n = BB * NN * 3;

    // How many j-split slices fit in the workspace? (power of 2, <= 16)
    size_t slice_bytes = (size_t)n * sizeof(float);
    int jb = 0;
    if (ws_size >= slice_bytes) {
        int fit = (int)(ws_size / slice_bytes);
        if (fit > MAXJB) fit = MAXJB;
        jb = 1;
        while (jb * 2 <= fit) jb *= 2;
    }

    if (jb >= 1) {
        ncp_partial<<<dim3(NN / TI, jb, BB), TI, 0, stream>>>(
            coords, radii, (float*)d_ws, jb);
        ncp_reduce<<<(n + 255) / 256, 256, 0, stream>>>(
            coords, (float*)d_ws, out, jb);
    } else {
        ncp_direct<<<dim3(NN / TI, 1, BB), TI, 0, stream>>>(coords, radii, out);
    }
}

// Round 2
// 81.141 us; speedup vs baseline: 1.0876x; 1.0876x over previous
//
#include <hip/hip_runtime.h>

#define BB 4
#define NN 4096
#define TI 256      // threads per block = i's per block
#define JB 32       // j-slices (grid.y) -> 2048 blocks, 8 blocks/CU, 32 waves/CU
#define JLEN (NN / JB)   // 128 j's per slice, staged once in LDS

#if __has_builtin(__builtin_amdgcn_sqrtf)
  #define FAST_SQRT __builtin_amdgcn_sqrtf
#else
  #define FAST_SQRT sqrtf
#endif

__device__ __forceinline__ float clip1(float x) {
    return fminf(fmaxf(x, -1.0f), 1.0f);   // -> v_med3_f32
}

// Per-(b,i) partial adjustment sums over j-slice blockIdx.y.
// part layout: [JB][BB*NN*3]
// Early-out: target = max(1, ri+rj) <= 2 always (radii in [0,1]), so if
// d2 >= 4 >= target^2 for ALL 64 lanes, the contribution is exactly 0.
__global__ __launch_bounds__(TI) void ncp_partial(
    const float* __restrict__ coords,   // [BB,NN,3]
    const float* __restrict__ radii,    // [BB,NN]
    float* __restrict__ part)
{
    __shared__ float4 jt[JLEN];
    const int b = blockIdx.z;
    const int i = blockIdx.x * TI + threadIdx.x;
    const int s = blockIdx.y;
    const int jbase = s * JLEN;

    if (threadIdx.x < JLEN) {
        const int jj = jbase + threadIdx.x;
        jt[threadIdx.x] = make_float4(coords[(b * NN + jj) * 3 + 0],
                                      coords[(b * NN + jj) * 3 + 1],
                                      coords[(b * NN + jj) * 3 + 2],
                                      radii[b * NN + jj]);
    }

    const float xi = coords[(b * NN + i) * 3 + 0];
    const float yi = coords[(b * NN + i) * 3 + 1];
    const float zi = coords[(b * NN + i) * 3 + 2];
    const float ri = radii[b * NN + i];

    float ax = 0.0f, ay = 0.0f, az = 0.0f;

    __syncthreads();

    #pragma unroll 4
    for (int k = 0; k < JLEN; ++k) {
        const float4 c = jt[k];                 // wave-uniform addr -> LDS broadcast
        const float dx = xi - c.x;
        const float dy = yi - c.y;
        const float dz = zi - c.z;
        const float d2 = fmaf(dx, dx, fmaf(dy, dy, dz * dz));
        if (__any(d2 < 4.0f)) {                 // wave-uniform branch
            const float dist = FAST_SQRT(d2);   // sqrt(0)=0 handles diagonal
            const float tgt = fmaxf(1.0f, ri + c.w);
            const float p = fmaxf(tgt - dist, 0.0f);
            ax = fmaf(p, clip1(dx), ax);
            ay = fmaf(p, clip1(dy), ay);
            az = fmaf(p, clip1(dz), az);
        }
    }

    float* dst = part + (size_t)s * (BB * NN * 3);
    const int o = (b * NN + i) * 3;
    dst[o + 0] = ax;
    dst[o + 1] = ay;
    dst[o + 2] = az;
}

// out[o] = coords[o] + 0.1/NN * sum_s part[s][o]
__global__ __launch_bounds__(256) void ncp_reduce(
    const float* __restrict__ coords,
    const float* __restrict__ part,
    float* __restrict__ out)
{
    const int o = blockIdx.x * 256 + threadIdx.x;
    if (o >= BB * NN * 3) return;
    float acc = 0.0f;
    #pragma unroll
    for (int s = 0; s < JB; ++s)
        acc += part[(size_t)s * (BB * NN * 3) + o];
    out[o] = fmaf(0.1f / (float)NN, acc, coords[o]);
}

// Fallback if ws can't hold JB slices: full j-loop per thread, direct store.
__global__ __launch_bounds__(TI) void ncp_direct(
    const float* __restrict__ coords,
    const float* __restrict__ radii,
    float* __restrict__ out)
{
    __shared__ float4 jt[TI];
    const int b = blockIdx.z;
    const int i = blockIdx.x * TI + threadIdx.x;

    const float xi = coords[(b * NN + i) * 3 + 0];
    const float yi = coords[(b * NN + i) * 3 + 1];
    const float zi = coords[(b * NN + i) * 3 + 2];
    const float ri = radii[b * NN + i];

    float ax = 0.0f, ay = 0.0f, az = 0.0f;

    for (int jc = 0; jc < NN; jc += TI) {
        const int jj = jc + threadIdx.x;
        __syncthreads();
        jt[threadIdx.x] = make_float4(coords[(b * NN + jj) * 3 + 0],
                                      coords[(b * NN + jj) * 3 + 1],
                                      coords[(b * NN + jj) * 3 + 2],
                                      radii[b * NN + jj]);
        __syncthreads();
        #pragma unroll 4
        for (int k = 0; k < TI; ++k) {
            const float4 c = jt[k];
            const float dx = xi - c.x;
            const float dy = yi - c.y;
            const float dz = zi - c.z;
            const float d2 = fmaf(dx, dx, fmaf(dy, dy, dz * dz));
            if (__any(d2 < 4.0f)) {
                const float dist = FAST_SQRT(d2);
                const float tgt = fmaxf(1.0f, ri + c.w);
                const float p = fmaxf(tgt - dist, 0.0f);
                ax = fmaf(p, clip1(dx), ax);
                ay = fmaf(p, clip1(dy), ay);
                az = fmaf(p, clip1(dz), az);
            }
        }
    }

    const int o = (b * NN + i) * 3;
    const float sc = 0.1f / (float)NN;
    out[o + 0] = fmaf(sc, ax, coords[o + 0]);
    out[o + 1] = fmaf(sc, ay, coords[o + 1]);
    out[o + 2] = fmaf(sc, az, coords[o + 2]);
}

extern "C" void kernel_launch(void* const* d_in, const int* in_sizes, int n_in,
                              void* d_out, int out_size, void* d_ws, size_t ws_size,
                              hipStream_t stream) {
    const float* coords = (const float*)d_in[0];
    const float* radii  = (const float*)d_in[1];
    float* out = (float*)d_out;
    const int n = BB * NN * 3;
    const size_t need = (size_t)JB * n * sizeof(float);

    if (ws_size >= need) {
        ncp_partial<<<dim3(NN / TI, JB, BB), TI, 0, stream>>>(
            coords, radii, (float*)d_ws);
        ncp_reduce<<<(n + 255) / 256, 256, 0, stream>>>(
            coords, (float*)d_ws, out);
    } else {
        ncp_direct<<<dim3(NN / TI, 1, BB), TI, 0, stream>>>(coords, radii, out);
    }
}

// Round 3
// 81.121 us; speedup vs baseline: 1.0879x; 1.0003x over previous
//
#include <hip/hip_runtime.h>

#define BB 4
#define NN 4096
#define TI 256      // threads per block = i's per block
#define JB 32       // j-slices (grid.y) -> 2048 blocks, 8 blocks/CU
#define JLEN (NN / JB)   // 128 j's per slice

#if __has_builtin(__builtin_amdgcn_sqrtf)
  #define FAST_SQRT __builtin_amdgcn_sqrtf
#else
  #define FAST_SQRT sqrtf
#endif

__device__ __forceinline__ float clip1(float x) {
    return fminf(fmaxf(x, -1.0f), 1.0f);   // -> v_med3_f32
}

// ws layout: [0, 256KB)          packed float4(x,y,z,r) [BB*NN]
//            [256KB, 256KB+6.3MB) part slices [JB][BB*NN*3]
#define PACK_ELEMS (BB * NN)
#define PART_OFF   (PACK_ELEMS * 4)   // in floats

__global__ __launch_bounds__(256) void ncp_pack(
    const float* __restrict__ coords,   // [BB,NN,3]
    const float* __restrict__ radii,    // [BB,NN]
    float4* __restrict__ packed)
{
    const int t = blockIdx.x * 256 + threadIdx.x;
    if (t >= PACK_ELEMS) return;
    packed[t] = make_float4(coords[t * 3 + 0], coords[t * 3 + 1],
                            coords[t * 3 + 2], radii[t]);
}

// Per-(b,i) partial sums over j-slice blockIdx.y. No LDS: the j-stream
// address is wave-uniform -> scalar/broadcast loads from L1/L2.
// Early-out: target = max(1, ri+rj) <= 2 (radii in [0,1]); d2 >= 4 -> exact 0.
__global__ __launch_bounds__(TI) void ncp_partial(
    const float4* __restrict__ packed,  // [BB*NN]
    float* __restrict__ part)
{
    const int b = blockIdx.z;
    const int i = blockIdx.x * TI + threadIdx.x;
    const int s = blockIdx.y;
    const float4* jsrc = packed + b * NN + s * JLEN;

    const float4 me = packed[b * NN + i];   // per-lane, coalesced
    const float xi = me.x, yi = me.y, zi = me.z, ri = me.w;

    float ax = 0.0f, ay = 0.0f, az = 0.0f;

    #pragma unroll 4
    for (int k = 0; k < JLEN; ++k) {
        const float4 c = jsrc[k];           // wave-uniform address
        const float dx = xi - c.x;
        const float dy = yi - c.y;
        const float dz = zi - c.z;
        const float d2 = fmaf(dx, dx, fmaf(dy, dy, dz * dz));
        if (__any(d2 < 4.0f)) {             // wave-uniform branch
            const float dist = FAST_SQRT(d2);   // sqrt(0)=0 -> diagonal ok
            const float tgt = fmaxf(1.0f, ri + c.w);
            const float p = fmaxf(tgt - dist, 0.0f);
            ax = fmaf(p, clip1(dx), ax);
            ay = fmaf(p, clip1(dy), ay);
            az = fmaf(p, clip1(dz), az);
        }
    }

    float* dst = part + (size_t)s * (BB * NN * 3);
    const int o = (b * NN + i) * 3;
    dst[o + 0] = ax;
    dst[o + 1] = ay;
    dst[o + 2] = az;
}

// out[o] = coords[o] + 0.1/NN * sum_s part[s][o]
__global__ __launch_bounds__(256) void ncp_reduce(
    const float* __restrict__ coords,
    const float* __restrict__ part,
    float* __restrict__ out)
{
    const int o = blockIdx.x * 256 + threadIdx.x;
    if (o >= BB * NN * 3) return;
    float acc = 0.0f;
    #pragma unroll
    for (int s = 0; s < JB; ++s)
        acc += part[(size_t)s * (BB * NN * 3) + o];
    out[o] = fmaf(0.1f / (float)NN, acc, coords[o]);
}

// Fallback if ws too small (LDS staging version, correctness backstop).
__global__ __launch_bounds__(TI) void ncp_direct(
    const float* __restrict__ coords,
    const float* __restrict__ radii,
    float* __restrict__ out)
{
    __shared__ float4 jt[TI];
    const int b = blockIdx.z;
    const int i = blockIdx.x * TI + threadIdx.x;

    const float xi = coords[(b * NN + i) * 3 + 0];
    const float yi = coords[(b * NN + i) * 3 + 1];
    const float zi = coords[(b * NN + i) * 3 + 2];
    const float ri = radii[b * NN + i];

    float ax = 0.0f, ay = 0.0f, az = 0.0f;

    for (int jc = 0; jc < NN; jc += TI) {
        const int jj = jc + threadIdx.x;
        __syncthreads();
        jt[threadIdx.x] = make_float4(coords[(b * NN + jj) * 3 + 0],
                                      coords[(b * NN + jj) * 3 + 1],
                                      coords[(b * NN + jj) * 3 + 2],
                                      radii[b * NN + jj]);
        __syncthreads();
        #pragma unroll 4
        for (int k = 0; k < TI; ++k) {
            const float4 c = jt[k];
            const float dx = xi - c.x;
            const float dy = yi - c.y;
            const float dz = zi - c.z;
            const float d2 = fmaf(dx, dx, fmaf(dy, dy, dz * dz));
            if (__any(d2 < 4.0f)) {
                const float dist = FAST_SQRT(d2);
                const float tgt = fmaxf(1.0f, ri + c.w);
                const float p = fmaxf(tgt - dist, 0.0f);
                ax = fmaf(p, clip1(dx), ax);
                ay = fmaf(p, clip1(dy), ay);
                az = fmaf(p, clip1(dz), az);
            }
        }
    }

    const int o = (b * NN + i) * 3;
    const float sc = 0.1f / (float)NN;
    out[o + 0] = fmaf(sc, ax, coords[o + 0]);
    out[o + 1] = fmaf(sc, ay, coords[o + 1]);
    out[o + 2] = fmaf(sc, az, coords[o + 2]);
}

extern "C" void kernel_launch(void* const* d_in, const int* in_sizes, int n_in,
                              void* d_out, int out_size, void* d_ws, size_t ws_size,
                              hipStream_t stream) {
    const float* coords = (const float*)d_in[0];
    const float* radii  = (const float*)d_in[1];
    float* out = (float*)d_out;
    const int n = BB * NN * 3;
    const size_t need = (size_t)(PART_OFF + (size_t)JB * n) * sizeof(float);

    if (ws_size >= need) {
        float4* packed = (float4*)d_ws;
        float* part = (float*)d_ws + PART_OFF;
        ncp_pack<<<(PACK_ELEMS + 255) / 256, 256, 0, stream>>>(coords, radii, packed);
        ncp_partial<<<dim3(NN / TI, JB, BB), TI, 0, stream>>>(packed, part);
        ncp_reduce<<<(n + 255) / 256, 256, 0, stream>>>(coords, part, out);
    } else {
        ncp_direct<<<dim3(NN / TI, 1, BB), TI, 0, stream>>>(coords, radii, out);
    }
}

// Round 4
// 79.740 us; speedup vs baseline: 1.1067x; 1.0173x over previous
//
#include <hip/hip_runtime.h>

#define BB 4
#define NN 4096
#define TI 256      // threads per block = i's per block
#define JB 32       // j-slices (grid.y) -> 2048 blocks, 8 blocks/CU
#define JLEN (NN / JB)   // 128 j's per slice
#define GRP 8       // loads in flight per pipeline group

#if __has_builtin(__builtin_amdgcn_sqrtf)
  #define FAST_SQRT __builtin_amdgcn_sqrtf
#else
  #define FAST_SQRT sqrtf
#endif

__device__ __forceinline__ float clip1(float x) {
    return fminf(fmaxf(x, -1.0f), 1.0f);   // -> v_med3_f32
}

// ws layout: [0, 256KB)           packed float4(x,y,z,r) [BB*NN]
//            [256KB, ...)         part slices [JB][BB*NN*3]
#define PACK_ELEMS (BB * NN)
#define PART_OFF   (PACK_ELEMS * 4)   // in floats

__global__ __launch_bounds__(256) void ncp_pack(
    const float* __restrict__ coords,   // [BB,NN,3]
    const float* __restrict__ radii,    // [BB,NN]
    float4* __restrict__ packed)
{
    const int t = blockIdx.x * 256 + threadIdx.x;
    if (t >= PACK_ELEMS) return;
    packed[t] = make_float4(coords[t * 3 + 0], coords[t * 3 + 1],
                            coords[t * 3 + 2], radii[t]);
}

// Per-(b,i) partial sums over j-slice blockIdx.y.
// Software-pipelined: phase 1 issues GRP uniform loads + d2 math branch-free
// (keeps GRP loads in flight); phase 2 runs the cheap early-out bodies on
// registers only. Early-out is exact: target = max(1, ri+rj) <= 2, so
// d2 >= 4 -> relu(target - dist) == 0.
__global__ __launch_bounds__(TI) void ncp_partial(
    const float4* __restrict__ packed,  // [BB*NN]
    float* __restrict__ part)
{
    const int b = blockIdx.z;
    const int i = blockIdx.x * TI + threadIdx.x;
    const int s = blockIdx.y;
    const float4* jsrc = packed + b * NN + s * JLEN;

    const float4 me = packed[b * NN + i];   // per-lane, coalesced
    const float xi = me.x, yi = me.y, zi = me.z, ri = me.w;

    float ax = 0.0f, ay = 0.0f, az = 0.0f;

    for (int k0 = 0; k0 < JLEN; k0 += GRP) {
        float dx[GRP], dy[GRP], dz[GRP], d2[GRP], rj[GRP];
        #pragma unroll
        for (int u = 0; u < GRP; ++u) {
            const float4 c = jsrc[k0 + u];      // uniform addr; 8 in flight
            dx[u] = xi - c.x;
            dy[u] = yi - c.y;
            dz[u] = zi - c.z;
            d2[u] = fmaf(dx[u], dx[u], fmaf(dy[u], dy[u], dz[u] * dz[u]));
            rj[u] = c.w;
        }
        #pragma unroll
        for (int u = 0; u < GRP; ++u) {
            if (__any(d2[u] < 4.0f)) {          // wave-uniform branch
                const float dist = FAST_SQRT(d2[u]);  // sqrt(0)=0 -> diag ok
                const float tgt = fmaxf(1.0f, ri + rj[u]);
                const float p = fmaxf(tgt - dist, 0.0f);
                ax = fmaf(p, clip1(dx[u]), ax);
                ay = fmaf(p, clip1(dy[u]), ay);
                az = fmaf(p, clip1(dz[u]), az);
            }
        }
    }

    float* dst = part + (size_t)s * (BB * NN * 3);
    const int o = (b * NN + i) * 3;
    dst[o + 0] = ax;
    dst[o + 1] = ay;
    dst[o + 2] = az;
}

// out[o] = coords[o] + 0.1/NN * sum_s part[s][o]   (ascending s == ascending j
// -> bitwise-matches reference sum order for the sparse nonzero terms)
__global__ __launch_bounds__(256) void ncp_reduce(
    const float* __restrict__ coords,
    const float* __restrict__ part,
    float* __restrict__ out)
{
    const int o = blockIdx.x * 256 + threadIdx.x;
    if (o >= BB * NN * 3) return;
    float acc = 0.0f;
    #pragma unroll
    for (int s = 0; s < JB; ++s)
        acc += part[(size_t)s * (BB * NN * 3) + o];
    out[o] = fmaf(0.1f / (float)NN, acc, coords[o]);
}

// Fallback if ws too small (LDS staging version, correctness backstop).
__global__ __launch_bounds__(TI) void ncp_direct(
    const float* __restrict__ coords,
    const float* __restrict__ radii,
    float* __restrict__ out)
{
    __shared__ float4 jt[TI];
    const int b = blockIdx.z;
    const int i = blockIdx.x * TI + threadIdx.x;

    const float xi = coords[(b * NN + i) * 3 + 0];
    const float yi = coords[(b * NN + i) * 3 + 1];
    const float zi = coords[(b * NN + i) * 3 + 2];
    const float ri = radii[b * NN + i];

    float ax = 0.0f, ay = 0.0f, az = 0.0f;

    for (int jc = 0; jc < NN; jc += TI) {
        const int jj = jc + threadIdx.x;
        __syncthreads();
        jt[threadIdx.x] = make_float4(coords[(b * NN + jj) * 3 + 0],
                                      coords[(b * NN + jj) * 3 + 1],
                                      coords[(b * NN + jj) * 3 + 2],
                                      radii[b * NN + jj]);
        __syncthreads();
        #pragma unroll 4
        for (int k = 0; k < TI; ++k) {
            const float4 c = jt[k];
            const float dx = xi - c.x;
            const float dy = yi - c.y;
            const float dz = zi - c.z;
            const float d2 = fmaf(dx, dx, fmaf(dy, dy, dz * dz));
            if (__any(d2 < 4.0f)) {
                const float dist = FAST_SQRT(d2);
                const float tgt = fmaxf(1.0f, ri + c.w);
                const float p = fmaxf(tgt - dist, 0.0f);
                ax = fmaf(p, clip1(dx), ax);
                ay = fmaf(p, clip1(dy), ay);
                az = fmaf(p, clip1(dz), az);
            }
        }
    }

    const int o = (b * NN + i) * 3;
    const float sc = 0.1f / (float)NN;
    out[o + 0] = fmaf(sc, ax, coords[o + 0]);
    out[o + 1] = fmaf(sc, ay, coords[o + 1]);
    out[o + 2] = fmaf(sc, az, coords[o + 2]);
}

extern "C" void kernel_launch(void* const* d_in, const int* in_sizes, int n_in,
                              void* d_out, int out_size, void* d_ws, size_t ws_size,
                              hipStream_t stream) {
    const float* coords = (const float*)d_in[0];
    const float* radii  = (const float*)d_in[1];
    float* out = (float*)d_out;
    const int n = BB * NN * 3;
    const size_t need = (size_t)(PART_OFF + (size_t)JB * n) * sizeof(float);

    if (ws_size >= need) {
        float4* packed = (float4*)d_ws;
        float* part = (float*)d_ws + PART_OFF;
        ncp_pack<<<(PACK_ELEMS + 255) / 256, 256, 0, stream>>>(coords, radii, packed);
        ncp_partial<<<dim3(NN / TI, JB, BB), TI, 0, stream>>>(packed, part);
        ncp_reduce<<<(n + 255) / 256, 256, 0, stream>>>(coords, part, out);
    } else {
        ncp_direct<<<dim3(NN / TI, 1, BB), TI, 0, stream>>>(coords, radii, out);
    }
}